// Round 7
// baseline (264.840 us; speedup 1.0000x reference)
//
#include <hip/hip_runtime.h>

// ---------------------------------------------------------------------------
// TransVLAD fused pipeline for MI355X (gfx950)
// Shapes: N=32, C=512, H=W=32 (P=1024), E=1024, G=8, D=128, K=64
// out: [N, K*D] fp32 (262144)
//
// R7: (a) K4 grid 512->1024 (qt quarters) w/ disjoint agg_part[N][G][4][K][D]
// (33.6MB; ws total 132.5MB). LDS 35.8KB (BK32 S-tiles aliased under
// half-staged xglds) -> 4 blocks/CU. K4 was grid-capped at 2 blocks/CU.
// (b) k3a fused into K2 epilogue (att partials from resident fp32 acc) --
// kills k3a's launch + 64MB xe re-read. k4c reduces wsum partials.
// ---------------------------------------------------------------------------

#define N_  32
#define C_  512
#define P_  1024
#define E_  1024
#define G_  8
#define D_  128
#define K_  64

typedef __attribute__((ext_vector_type(8))) short bf16x8;
typedef __attribute__((ext_vector_type(4))) float f32x4;

__device__ __forceinline__ unsigned short f2b(float f) {
    union { float f; unsigned u; } v; v.f = f;
    unsigned r = (v.u + 0x7FFFu + ((v.u >> 16) & 1u)) >> 16;
    return (unsigned short)r;
}
__device__ __forceinline__ float b2f(unsigned short h) {
    union { unsigned u; float f; } v; v.u = ((unsigned)h) << 16;
    return v.f;
}

// async global->LDS 16B copy: LDS dest must be wave-uniform base + lane*16
__device__ __forceinline__ void gl_lds16(const void* g, void* l) {
    __builtin_amdgcn_global_load_lds(
        (const __attribute__((address_space(1))) void*)g,
        (__attribute__((address_space(3))) void*)l, 16, 0, 0);
}

// ---------------------------------------------------------------------------
// K0: convert W1 -> bf16 AND build V[g][k][c] = sum_d Wc[k][d]*W1[g*128+d][c]
__global__ __launch_bounds__(256) void k0_prep(const float* __restrict__ W1,
                                               const float* __restrict__ Wc,
                                               unsigned short* __restrict__ W1b,
                                               unsigned short* __restrict__ Vb) {
    int bid = blockIdx.x;
    int t = threadIdx.x;
    int i0 = bid * 512 + t;
    W1b[i0]       = f2b(W1[i0]);
    W1b[i0 + 256] = f2b(W1[i0 + 256]);
    int ch = bid & 1, k = (bid >> 1) & 63, g = bid >> 7;
    int c = ch * 256 + t;
    float acc = 0.f;
    #pragma unroll 8
    for (int d = 0; d < 128; ++d)
        acc += Wc[k * 128 + d] * W1[(g * 128 + d) * C_ + c];
    Vb[(g * 64 + k) * C_ + c] = f2b(acc);
}

// ---------------------------------------------------------------------------
// K1: per-pixel L2 norm over C, write x_hat transposed: xhat_t [N][P][C] bf16
__global__ __launch_bounds__(256) void k1_norm_transpose(const float* __restrict__ x,
                                                         unsigned short* __restrict__ xhat_t) {
    __shared__ short xc[128 * 256];
    __shared__ float red[256];
    __shared__ float rn[64];
    int n = blockIdx.y;
    int p0 = blockIdx.x * 64;
    int t = threadIdx.x;
    int ps = t & 63, cs = t >> 6;

    float ss = 0.f;
    for (int i = 0; i < 128; ++i) {
        float v = x[((size_t)(n * C_ + cs * 128 + i)) * P_ + p0 + ps];
        ss += v * v;
        xc[i * 256 + t] = (short)f2b(v);
    }
    red[t] = ss;
    __syncthreads();
    if (t < 64) {
        float s = red[t] + red[64 + t] + red[128 + t] + red[192 + t];
        rn[t] = 1.0f / fmaxf(sqrtf(s), 1e-12f);
    }
    __syncthreads();

    float r = rn[ps];
    size_t base = ((size_t)(n * P_ + p0 + ps)) * C_ + cs * 128;
    #pragma unroll
    for (int jj = 0; jj < 16; ++jj) {
        bf16x8 o;
        #pragma unroll
        for (int j = 0; j < 8; ++j)
            o[j] = (short)f2b(b2f((unsigned short)xc[(jj * 8 + j) * 256 + t]) * r);
        *(bf16x8*)&xhat_t[base + jj * 8] = o;
    }
}

// ---------------------------------------------------------------------------
// K2: xe[n][e][p] = sum_c W1b[e][c] * xhat_t[n][p][c]  (bf16 MFMA, BK=64)
// + FUSED att partials: att_part[n][eblk*2+wr][g][p] from resident fp32 acc.
// grid (64, 32): e0 = (bx>>3)*128, p0 = (bx&7)*128, n = by.
__global__ __launch_bounds__(256) void k2_gemm_xe(const unsigned short* __restrict__ W1b,
                                                  const unsigned short* __restrict__ xhat_t,
                                                  const float* __restrict__ W2,
                                                  unsigned short* __restrict__ xe,
                                                  float* __restrict__ att_part) {
    __shared__ __align__(16) short As[128 * 64];
    __shared__ __align__(16) short Bs[128 * 64];
    int n = blockIdx.y;
    int e0 = (blockIdx.x >> 3) * 128;
    int p0 = (blockIdx.x & 7) * 128;
    int t = threadIdx.x;
    int w = t >> 6, l = t & 63, q = l >> 4, l15 = l & 15;
    int wr = w >> 1, wc = w & 1;

    f32x4 acc[4][4];
    #pragma unroll
    for (int mi = 0; mi < 4; ++mi)
        #pragma unroll
        for (int ni = 0; ni < 4; ++ni)
            acc[mi][ni] = (f32x4){0.f, 0.f, 0.f, 0.f};

    for (int ks = 0; ks < 8; ++ks) {
        int k0 = ks * 64;
        #pragma unroll
        for (int i = 0; i < 4; ++i) {
            int ch = i * 256 + t;
            int row = ch >> 3, col = (ch & 7) * 8;
            gl_lds16(&W1b[(e0 + row) * C_ + k0 + col], &As[ch * 8]);
        }
        #pragma unroll
        for (int i = 0; i < 4; ++i) {
            int ch = i * 256 + t;
            int row = ch >> 3, col = (ch & 7) * 8;
            gl_lds16(&xhat_t[((size_t)(n * P_ + p0 + row)) * C_ + k0 + col], &Bs[ch * 8]);
        }
        __syncthreads();

        #pragma unroll
        for (int kk = 0; kk < 2; ++kk) {
            bf16x8 af[4], bf[4];
            #pragma unroll
            for (int mi = 0; mi < 4; ++mi)
                af[mi] = *(const bf16x8*)&As[(wr * 64 + mi * 16 + l15) * 64 + kk * 32 + q * 8];
            #pragma unroll
            for (int ni = 0; ni < 4; ++ni)
                bf[ni] = *(const bf16x8*)&Bs[(wc * 64 + ni * 16 + l15) * 64 + kk * 32 + q * 8];
            #pragma unroll
            for (int mi = 0; mi < 4; ++mi)
                #pragma unroll
                for (int ni = 0; ni < 4; ++ni)
                    acc[mi][ni] = __builtin_amdgcn_mfma_f32_16x16x32_bf16(af[mi], bf[ni], acc[mi][ni], 0, 0, 0);
        }
        __syncthreads();
    }

    // xe write-out
    #pragma unroll
    for (int mi = 0; mi < 4; ++mi) {
        #pragma unroll
        for (int ni = 0; ni < 4; ++ni) {
            #pragma unroll
            for (int r = 0; r < 4; ++r) {
                int e = e0 + wr * 64 + mi * 16 + q * 4 + r;
                int p = p0 + wc * 64 + ni * 16 + l15;
                xe[((size_t)(n * E_ + e)) * P_ + p] = f2b(acc[mi][ni][r]);
            }
        }
    }

    // ---- fused attention partials (kills old k3a) ----
    float* w2l = (float*)As;   // 4 KB, aliases As (dead after K-loop barrier)
    #pragma unroll
    for (int i = 0; i < 4; ++i) {
        int idx = i * 256 + t;                  // [8][128]: g = idx>>7, el = idx&127
        w2l[idx] = W2[(idx >> 7) * E_ + e0 + (idx & 127)];
    }
    __syncthreads();
    int slot = (blockIdx.x >> 3) * 2 + wr;      // 0..15
    #pragma unroll
    for (int gg = 0; gg < 8; ++gg) {
        float pa[4] = {0.f, 0.f, 0.f, 0.f};
        #pragma unroll
        for (int mi = 0; mi < 4; ++mi)
            #pragma unroll
            for (int r = 0; r < 4; ++r) {
                float w2v = w2l[gg * 128 + wr * 64 + mi * 16 + q * 4 + r];
                #pragma unroll
                for (int ni = 0; ni < 4; ++ni)
                    pa[ni] += acc[mi][ni][r] * w2v;
            }
        #pragma unroll
        for (int ni = 0; ni < 4; ++ni) {
            pa[ni] += __shfl_xor(pa[ni], 16);
            pa[ni] += __shfl_xor(pa[ni], 32);
        }
        if (q == 0) {
            size_t ab = (((size_t)(n * 16 + slot)) * 8 + gg) * P_ + p0 + wc * 64;
            #pragma unroll
            for (int ni = 0; ni < 4; ++ni)
                att_part[ab + ni * 16 + l15] = pa[ni];
        }
    }
}

// K3b: att_s[n][g][p] = sigmoid( sum_slot att_part[n][slot][g][p] )
__global__ __launch_bounds__(256) void k3b_att_reduce(const float* __restrict__ att_part,
                                                      float* __restrict__ att_s) {
    int idx = blockIdx.x * 256 + threadIdx.x;   // grid 1024 -> 262144
    int p = idx & 1023;
    int g = (idx >> 10) & 7;
    int n = idx >> 13;
    float s = 0.f;
    #pragma unroll
    for (int sl = 0; sl < 16; ++sl)
        s += att_part[(((size_t)(n * 16 + sl)) * 8 + g) * P_ + p];
    att_s[idx] = 1.0f / (1.0f + __expf(-s));
}

// ---------------------------------------------------------------------------
// K4: fused assignment -> softmax -> gate -> aggregation per (n, g, qt)
// grid (32, 32): bx = qt + 4*g (XCD-pairs share the xhat tile), n = by.
// Per block: 2 cc iters of 128 px. LDS 35.8KB -> 4 blocks/CU.
__global__ __launch_bounds__(256) void k4_assign_agg(const unsigned short* __restrict__ Vb,
                                                     const unsigned short* __restrict__ xhat_t,
                                                     const unsigned short* __restrict__ xe,
                                                     const float* __restrict__ att_s,
                                                     float* __restrict__ agg_part,
                                                     float* __restrict__ wsum_part) {
    __shared__ __align__(16) char smem[18432 + 17408];
    short* As2   = (short*)smem;                // [64][32]   4 KB (S phase)
    short* Bs2   = (short*)(smem + 4096);       // [128][32]  8 KB (S phase)
    short* xglds = (short*)smem;                // [128][72] 18 KB (agg phase, aliases S tiles)
    short* wlds  = (short*)(smem + 18432);      // [64][136] 17 KB

    int bx = blockIdx.x;
    int qt = bx & 3, g = bx >> 2, n = blockIdx.y;
    int t = threadIdx.x;
    int w = t >> 6, l = t & 63, q = l >> 4, l15 = l & 15;

    f32x4 acc_a[4][2];
    #pragma unroll
    for (int mi = 0; mi < 4; ++mi)
        #pragma unroll
        for (int ni = 0; ni < 2; ++ni)
            acc_a[mi][ni] = (f32x4){0.f, 0.f, 0.f, 0.f};
    float wsp[16];
    #pragma unroll
    for (int j = 0; j < 16; ++j) wsp[j] = 0.f;

    for (int cc = 0; cc < 2; ++cc) {
        int p0c = qt * 256 + cc * 128;

        // ---- Phase S: S = Vb[g] (64xC) * xhat^T (Cx128), BK=32 ----
        f32x4 acc_s[4][2];
        #pragma unroll
        for (int mi = 0; mi < 4; ++mi)
            #pragma unroll
            for (int ni = 0; ni < 2; ++ni)
                acc_s[mi][ni] = (f32x4){0.f, 0.f, 0.f, 0.f};

        for (int ks = 0; ks < 16; ++ks) {
            int k0 = ks * 32;
            {   // As2: 64x32, 1 chunk/thread
                int row = t >> 2, col = (t & 3) * 8;
                gl_lds16(&Vb[(g * 64 + row) * C_ + k0 + col], &As2[t * 8]);
            }
            #pragma unroll
            for (int i = 0; i < 2; ++i) {   // Bs2: 128x32
                int ch = i * 256 + t;
                int row = ch >> 2, col = (ch & 3) * 8;
                gl_lds16(&xhat_t[((size_t)(n * P_ + p0c + row)) * C_ + k0 + col], &Bs2[ch * 8]);
            }
            __syncthreads();
            bf16x8 af[4], bf2[2];
            #pragma unroll
            for (int mi = 0; mi < 4; ++mi)
                af[mi] = *(const bf16x8*)&As2[(mi * 16 + l15) * 32 + q * 8];
            #pragma unroll
            for (int ni = 0; ni < 2; ++ni)
                bf2[ni] = *(const bf16x8*)&Bs2[(w * 32 + ni * 16 + l15) * 32 + q * 8];
            #pragma unroll
            for (int mi = 0; mi < 4; ++mi)
                #pragma unroll
                for (int ni = 0; ni < 2; ++ni)
                    acc_s[mi][ni] = __builtin_amdgcn_mfma_f32_16x16x32_bf16(af[mi], bf2[ni], acc_s[mi][ni], 0, 0, 0);
            __syncthreads();
        }

        // ---- softmax over k + gate (writes wlds only) ----
        #pragma unroll
        for (int ni = 0; ni < 2; ++ni) {
            float m = -1e30f;
            #pragma unroll
            for (int mi = 0; mi < 4; ++mi)
                #pragma unroll
                for (int r = 0; r < 4; ++r)
                    m = fmaxf(m, acc_s[mi][ni][r]);
            m = fmaxf(m, __shfl_xor(m, 16));
            m = fmaxf(m, __shfl_xor(m, 32));
            float s = 0.f;
            #pragma unroll
            for (int mi = 0; mi < 4; ++mi)
                #pragma unroll
                for (int r = 0; r < 4; ++r) {
                    float e = __expf(acc_s[mi][ni][r] - m);
                    acc_s[mi][ni][r] = e;
                    s += e;
                }
            s += __shfl_xor(s, 16);
            s += __shfl_xor(s, 32);

            int pcol = p0c + w * 32 + ni * 16 + l15;
            float av = att_s[(((size_t)(n * G_ + g)) * P_) + pcol];  // pre-sigmoided
            float scale = av / s;

            #pragma unroll
            for (int mi = 0; mi < 4; ++mi)
                #pragma unroll
                for (int r = 0; r < 4; ++r) {
                    float wv = acc_s[mi][ni][r] * scale;
                    wsp[mi * 4 + r] += wv;
                    wlds[(mi * 16 + q * 4 + r) * 136 + (w * 32 + ni * 16 + l15)] = (short)f2b(wv);
                }
        }

        // ---- agg in two 64-px halves: stage xglds (aliases S tiles) + MFMA ----
        for (int h = 0; h < 2; ++h) {
            // 128 rows x 9 chunks (72 shorts incl. pad) = 1152 chunks
            #pragma unroll
            for (int i = 0; i < 4; ++i) {
                int ch = i * 256 + t;
                int row = ch / 9, col = (ch % 9) * 8;
                gl_lds16(&xe[((size_t)(n * E_ + g * 128 + row)) * P_ + p0c + h * 64 + col],
                         &xglds[ch * 8]);
            }
            if (t < 128) {
                int ch = 1024 + t;
                int row = ch / 9, col = (ch % 9) * 8;
                gl_lds16(&xe[((size_t)(n * E_ + g * 128 + row)) * P_ + p0c + h * 64 + col],
                         &xglds[ch * 8]);
            }
            __syncthreads();   // drains DMA; covers wlds writes (h=0)

            #pragma unroll
            for (int pk = 0; pk < 2; ++pk) {
                bf16x8 a2[4], b2[2];
                #pragma unroll
                for (int mi = 0; mi < 4; ++mi)
                    a2[mi] = *(const bf16x8*)&wlds[(mi * 16 + l15) * 136 + h * 64 + pk * 32 + q * 8];
                #pragma unroll
                for (int ni = 0; ni < 2; ++ni)
                    b2[ni] = *(const bf16x8*)&xglds[(w * 32 + ni * 16 + l15) * 72 + pk * 32 + q * 8];
                #pragma unroll
                for (int mi = 0; mi < 4; ++mi)
                    #pragma unroll
                    for (int ni = 0; ni < 2; ++ni)
                        acc_a[mi][ni] = __builtin_amdgcn_mfma_f32_16x16x32_bf16(a2[mi], b2[ni], acc_a[mi][ni], 0, 0, 0);
            }
            __syncthreads();   // xglds reads done before restage / next cc S tiles
        }
    }

    // ---- epilogue: disjoint partials ----
    size_t base = (((size_t)(n * G_ + g)) * 4 + qt) * 64;
    #pragma unroll
    for (int mi = 0; mi < 4; ++mi)
        #pragma unroll
        for (int ni = 0; ni < 2; ++ni)
            #pragma unroll
            for (int r = 0; r < 4; ++r) {
                int k = mi * 16 + q * 4 + r;
                int d = w * 32 + ni * 16 + l15;
                agg_part[(base + k) * 128 + d] = acc_a[mi][ni][r];
            }

    #pragma unroll
    for (int j = 0; j < 16; ++j) {
        float v = wsp[j];
        v += __shfl_xor(v, 1);
        v += __shfl_xor(v, 2);
        v += __shfl_xor(v, 4);
        v += __shfl_xor(v, 8);
        if (l15 == 0) {
            int k = (j >> 2) * 16 + q * 4 + (j & 3);
            wsum_part[(base + 0) * 0 + ((((size_t)(n * G_ + g)) * 4 + qt) * 4 + w) * 64 + k] = v;
        }
    }
}

// k4c: wsum[n][k] = sum over (g, qt, wave) of wsum_part
__global__ __launch_bounds__(256) void k4c_wsum(const float* __restrict__ wsum_part,
                                                float* __restrict__ wsum) {
    int idx = blockIdx.x * 256 + threadIdx.x;   // grid 8 -> 2048
    int n = idx >> 6, k = idx & 63;
    float s = 0.f;
    #pragma unroll
    for (int g = 0; g < 8; ++g)
        #pragma unroll
        for (int qt = 0; qt < 4; ++qt)
            #pragma unroll
            for (int w2 = 0; w2 < 4; ++w2)
                s += wsum_part[((((size_t)(n * G_ + g)) * 4 + qt) * 4 + w2) * 64 + k];
    wsum[idx] = s;
}

// ---------------------------------------------------------------------------
// K5: vlad[n][k][d] = sum_{g,qt} agg_part - wsum[n][k] * centroids[k][d]
__global__ __launch_bounds__(256) void k5_final(const float* __restrict__ agg_part,
                                                const float* __restrict__ wsum,
                                                const float* __restrict__ centroids,
                                                float* __restrict__ out) {
    int idx = blockIdx.x * 256 + threadIdx.x;   // grid 1024 -> 262144
    int d = idx & 127;
    int k = (idx >> 7) & 63;
    int n = idx >> 13;
    float ag = 0.f;
    #pragma unroll
    for (int g = 0; g < 8; ++g)
        #pragma unroll
        for (int qt = 0; qt < 4; ++qt)
            ag += agg_part[((((size_t)(n * G_ + g)) * 4 + qt) * 64 + k) * 128 + d];
    out[idx] = ag - wsum[n * 64 + k] * centroids[k * 128 + d];
}

// ---------------------------------------------------------------------------
extern "C" void kernel_launch(void* const* d_in, const int* in_sizes, int n_in,
                              void* d_out, int out_size, void* d_ws, size_t ws_size,
                              hipStream_t stream) {
    const float* x         = (const float*)d_in[0];
    const float* W1        = (const float*)d_in[1];
    const float* W2        = (const float*)d_in[2];
    const float* Wc        = (const float*)d_in[3];
    const float* centroids = (const float*)d_in[4];
    float* out = (float*)d_out;

    // Workspace layout (total 138,944,512 B ~= 132.5 MB):
    //   W1b      [E*C]         bf16   1,048,576 B @ 0
    //   Vb       [G*K*C]       bf16     524,288 B @ 1,048,576
    //   xhat_t   [N*P*C]       bf16  33,554,432 B @ 1,572,864
    //   xe       [N*E*P]       bf16  67,108,864 B @ 35,127,296
    //   att_s    [N*G*P]       f32    1,048,576 B @ 102,236,160
    //   att_part [N*16*G*P]    f32   16,777,216 B @ 103,284,736 (dead after k3b;
    //   agg_part [N*G*4*K*D]   f32   33,554,432 B @ 103,284,736  aliased)
    //   wsum_part[N*G*4*4*K]   f32    2,097,152 B @ 136,839,168
    //   wsum     [N*K]         f32        8,192 B @ 138,936,320
    char* ws = (char*)d_ws;
    unsigned short* W1b      = (unsigned short*)(ws + 0);
    unsigned short* Vb       = (unsigned short*)(ws + 1048576);
    unsigned short* xhat_t   = (unsigned short*)(ws + 1572864);
    unsigned short* xe       = (unsigned short*)(ws + 35127296);
    float*          att_s    = (float*)(ws + 102236160);
    float*          att_part = (float*)(ws + 103284736);
    float*          agg_part = (float*)(ws + 103284736);   // alias: att_part dead before K4
    float*          wsum_part= (float*)(ws + 136839168);
    float*          wsum     = (float*)(ws + 138936320);

    hipLaunchKernelGGL(k0_prep,        dim3(1024), dim3(256), 0, stream, W1, Wc, W1b, Vb);
    hipLaunchKernelGGL(k1_norm_transpose, dim3(16, 32), dim3(256), 0, stream, x, xhat_t);
    hipLaunchKernelGGL(k2_gemm_xe,     dim3(64, 32), dim3(256), 0, stream,
                       W1b, xhat_t, W2, xe, att_part);
    hipLaunchKernelGGL(k3b_att_reduce, dim3(1024), dim3(256), 0, stream, att_part, att_s);
    hipLaunchKernelGGL(k4_assign_agg,  dim3(32, 32), dim3(256), 0, stream, Vb, xhat_t, xe,
                       att_s, agg_part, wsum_part);
    hipLaunchKernelGGL(k4c_wsum,       dim3(8), dim3(256), 0, stream, wsum_part, wsum);
    hipLaunchKernelGGL(k5_final,       dim3(1024), dim3(256), 0, stream,
                       agg_part, wsum, centroids, out);
}